// Round 7
// baseline (378.674 us; speedup 1.0000x reference)
//
#include <hip/hip_runtime.h>

// DistMult: out[n1,n2] = (input1 * w[type]) @ input2^T + bias
// n1=n2=8192, d=512, fp32 in/out.
// Pass 1: fp32->bf16 convert (w_r scale fused into A).
// Pass 2: 256x256 bf16 MFMA NT-GEMM, BK=64, 8 waves, DOUBLE-buffered 128 KiB
//         LDS with counted vmcnt(8): tile t+1's loads stay in flight across
//         the whole 64-MFMA compute phase (T3/T4 at 2-phase depth).
//         vs r6 (128x128 single-buf): staged L2/L3 traffic 1 GB -> 512 MB,
//         load latency hidden instead of drained every iteration.
// Staging swizzle (r6-verified involution): linear LDS dest, global source
// slot (lane&7)^(lane>>3); read slot (kk*4+quad)^(row&7) -> conflict-free.
// Known harness tax: ~170 us unconditional 1 GiB ws-poison fill (r3).

#define N1 8192
#define N2 8192
#define DK 512
#define BK 64
#define NT (DK / BK)

typedef short bf16x8 __attribute__((ext_vector_type(8)));
typedef float f32x4 __attribute__((ext_vector_type(4)));

#define FENCE() asm volatile("" ::: "memory")
#define VMC(n)  asm volatile("s_waitcnt vmcnt(" #n ")" ::: "memory")
#define BARR()  do { FENCE(); __builtin_amdgcn_s_barrier(); FENCE(); } while (0)

__device__ __forceinline__ unsigned short f2bf(float f) {
    unsigned int u = __float_as_uint(f);
    u = (u + 0x7FFFu + ((u >> 16) & 1u)) >> 16;  // round-to-nearest-even
    return (unsigned short)u;
}

// One pass over both inputs: A-region gets w_r scaling, B-region straight cast.
__global__ __launch_bounds__(256) void convert_kernel(
        const float* __restrict__ in1, const float* __restrict__ in2,
        const float* __restrict__ weight, const int* __restrict__ type_index,
        unsigned short* __restrict__ a_bf, unsigned short* __restrict__ b_bf) {
    const int QA = N1 * DK / 4;
    int i = blockIdx.x * blockDim.x + threadIdx.x;
    if (i < QA) {
        float4 v = reinterpret_cast<const float4*>(in1)[i];
        int c4 = i & (DK / 4 - 1);
        float4 w = reinterpret_cast<const float4*>(weight + (size_t)(*type_index) * DK)[c4];
        ushort4 o;
        o.x = f2bf(v.x * w.x);
        o.y = f2bf(v.y * w.y);
        o.z = f2bf(v.z * w.z);
        o.w = f2bf(v.w * w.w);
        reinterpret_cast<ushort4*>(a_bf)[i] = o;
    } else {
        int j = i - QA;
        float4 v = reinterpret_cast<const float4*>(in2)[j];
        ushort4 o;
        o.x = f2bf(v.x);
        o.y = f2bf(v.y);
        o.z = f2bf(v.z);
        o.w = f2bf(v.w);
        reinterpret_cast<ushort4*>(b_bf)[j] = o;
    }
}

// NT GEMM: C[m][n] = sum_k A[m][k]*B[n][k] + bias. A,B bf16 row-major [*,DK].
// 512 thr = 8 waves (2M x 4N); wave sub-tile 128x64; acc[8][4] f32x4.
// LDS: A0 0..32K | A1 32..64K | B0 64..96K | B1 96..128K (tile = [256][64]
// bf16, 128 B/row). Per thread per tile: 4 A-loads + 4 B-loads (16 B each).
__global__ __launch_bounds__(512, 1) void gemm_256(
        const unsigned short* __restrict__ A, const unsigned short* __restrict__ B,
        const float* __restrict__ bias, float* __restrict__ C) {
    extern __shared__ char sm[];
    const int tid  = threadIdx.x;
    const int wave = tid >> 6;
    const int lane = tid & 63;
    const int quad = lane >> 4;
    const int r16  = lane & 15;
    const int wm   = wave >> 2;   // 0..1
    const int wn   = wave & 3;    // 0..3

    const int bm = blockIdx.y * 256;
    const int bn = blockIdx.x * 256;

    f32x4 acc[8][4];
#pragma unroll
    for (int i = 0; i < 8; ++i)
#pragma unroll
        for (int j = 0; j < 4; ++j)
            acc[i][j] = (f32x4){0.f, 0.f, 0.f, 0.f};

    // Staging geometry: wave w covers tile rows [w*32, w*32+32) in 4 chunks
    // of 8 rows; lane -> row chunkbase + lane/8, LDS slot lane&7 (linear,
    // dest = wavebase + lane*16), global source slot (lane&7)^(lane>>3).
    const int l8   = lane >> 3;
    const int perm = (lane & 7) ^ l8;
    const unsigned short* ag = A + (size_t)(bm + wave * 32 + l8) * DK + perm * 8;
    const unsigned short* bg = B + (size_t)(bn + wave * 32 + l8) * DK + perm * 8;
    const int wbase = wave * 4096;  // bytes into a 32 KB tile buffer

    // Swizzled read col offsets (bytes) for kk=0 / kk=1.
    const int rs   = r16 & 7;
    const int col0 = ((0 * 4 + quad) ^ rs) * 16;
    const int col1 = ((1 * 4 + quad) ^ rs) * 16;
    const int rowA = (wm * 128 + r16) * 128;   // byte row base, A tile
    const int rowB = (wn * 64  + r16) * 128;   // byte row base, B tile

#define STAGE(T, BUF) do {                                                        \
    char* dA = sm + (BUF) * 32768 + wbase;                                        \
    char* dB = sm + 65536 + (BUF) * 32768 + wbase;                                \
    _Pragma("unroll") for (int i_ = 0; i_ < 4; ++i_) {                            \
        __builtin_amdgcn_global_load_lds(ag + (T) * BK + i_ * 8 * DK,             \
            (unsigned short*)(dA + i_ * 1024), 16, 0, 0);                         \
        __builtin_amdgcn_global_load_lds(bg + (T) * BK + i_ * 8 * DK,             \
            (unsigned short*)(dB + i_ * 1024), 16, 0, 0);                         \
    }                                                                             \
} while (0)

    STAGE(0, 0);

#pragma unroll 1
    for (int t = 0; t < NT; ++t) {
        const int cur = t & 1;
        if (t + 1 < NT) {
            STAGE(t + 1, cur ^ 1);
            VMC(8);                 // tile t resident (8 newest = tile t+1)
        } else {
            VMC(0);                 // tail: drain tile NT-1
        }
        BARR();                     // all waves' tile-t loads visible

        const char* bufA = sm + cur * 32768;
        const char* bufB = sm + 65536 + cur * 32768;

        // kk = 0 : k = t*64 .. +31
        {
            bf16x8 af[8], bfr[4];
#pragma unroll
            for (int mi = 0; mi < 8; ++mi)
                af[mi] = *(const bf16x8*)(bufA + rowA + mi * 2048 + col0);
#pragma unroll
            for (int ni = 0; ni < 4; ++ni)
                bfr[ni] = *(const bf16x8*)(bufB + rowB + ni * 2048 + col0);
#pragma unroll
            for (int mi = 0; mi < 8; ++mi)
#pragma unroll
                for (int ni = 0; ni < 4; ++ni)
                    acc[mi][ni] = __builtin_amdgcn_mfma_f32_16x16x32_bf16(
                        af[mi], bfr[ni], acc[mi][ni], 0, 0, 0);
        }
        // kk = 1 : k = t*64+32 .. +63
        {
            bf16x8 af[8], bfr[4];
#pragma unroll
            for (int mi = 0; mi < 8; ++mi)
                af[mi] = *(const bf16x8*)(bufA + rowA + mi * 2048 + col1);
#pragma unroll
            for (int ni = 0; ni < 4; ++ni)
                bfr[ni] = *(const bf16x8*)(bufB + rowB + ni * 2048 + col1);
#pragma unroll
            for (int mi = 0; mi < 8; ++mi)
#pragma unroll
                for (int ni = 0; ni < 4; ++ni)
                    acc[mi][ni] = __builtin_amdgcn_mfma_f32_16x16x32_bf16(
                        af[mi], bfr[ni], acc[mi][ni], 0, 0, 0);
        }
        BARR();   // all reads of buf[cur] done before iter t+1 overwrites it
    }
#undef STAGE

    // Epilogue: C/D mapping col=lane&15, row=quad*4+reg (verified m89/m91).
    const float bv = bias[0];
#pragma unroll
    for (int mi = 0; mi < 8; ++mi) {
        const int row0 = bm + wm * 128 + mi * 16 + quad * 4;
#pragma unroll
        for (int ni = 0; ni < 4; ++ni) {
            const int col = bn + wn * 64 + ni * 16 + r16;
#pragma unroll
            for (int r = 0; r < 4; ++r)
                C[(size_t)(row0 + r) * N2 + col] = acc[mi][ni][r] + bv;
        }
    }
}

// ---------------------------------------------------------------------------
// Fallback: r6-verified 128x128 BK=64 single-buffer kernel (340 us total).
// ---------------------------------------------------------------------------
__global__ __launch_bounds__(256) void gemm_bt(
        const unsigned short* __restrict__ A, const unsigned short* __restrict__ B,
        const float* __restrict__ bias, float* __restrict__ C) {
    __shared__ __align__(16) unsigned short ldsA[128 * BK];
    __shared__ __align__(16) unsigned short ldsB[128 * BK];

    const int tid  = threadIdx.x;
    const int wave = tid >> 6;
    const int lane = tid & 63;
    const int quad = lane >> 4;
    const int r16  = lane & 15;
    const int wm   = wave & 1;
    const int wn   = wave >> 1;

    const int bm = blockIdx.y * 128;
    const int bn = blockIdx.x * 128;

    f32x4 acc[4][4];
#pragma unroll
    for (int i = 0; i < 4; ++i)
#pragma unroll
        for (int j = 0; j < 4; ++j)
            acc[i][j] = (f32x4){0.f, 0.f, 0.f, 0.f};

    const int l8   = lane >> 3;
    const int perm = (lane & 7) ^ l8;
    const int srow = wave * 32 + l8;
    const int scol = perm * 8;
    const unsigned short* ag = A + (size_t)(bm + srow) * DK + scol;
    const unsigned short* bg = B + (size_t)(bn + srow) * DK + scol;
    unsigned short* la = &ldsA[wave * 2048];
    unsigned short* lb = &ldsB[wave * 2048];

    const int rs   = r16 & 7;
    const int col0 = ((0 * 4 + quad) ^ rs) * 8;
    const int col1 = ((1 * 4 + quad) ^ rs) * 8;

    for (int kt = 0; kt < DK; kt += BK) {
#pragma unroll
        for (int i = 0; i < 4; ++i) {
            __builtin_amdgcn_global_load_lds(ag + kt + i * 8 * DK, la + i * 512, 16, 0, 0);
            __builtin_amdgcn_global_load_lds(bg + kt + i * 8 * DK, lb + i * 512, 16, 0, 0);
        }
        __syncthreads();

        {
            bf16x8 af[4], bfr[4];
#pragma unroll
            for (int mi = 0; mi < 4; ++mi)
                af[mi] = *(const bf16x8*)&ldsA[(wm * 64 + mi * 16 + r16) * BK + col0];
#pragma unroll
            for (int ni = 0; ni < 4; ++ni)
                bfr[ni] = *(const bf16x8*)&ldsB[(wn * 64 + ni * 16 + r16) * BK + col0];
#pragma unroll
            for (int mi = 0; mi < 4; ++mi)
#pragma unroll
                for (int ni = 0; ni < 4; ++ni)
                    acc[mi][ni] = __builtin_amdgcn_mfma_f32_16x16x32_bf16(
                        af[mi], bfr[ni], acc[mi][ni], 0, 0, 0);
        }
        {
            bf16x8 af[4], bfr[4];
#pragma unroll
            for (int mi = 0; mi < 4; ++mi)
                af[mi] = *(const bf16x8*)&ldsA[(wm * 64 + mi * 16 + r16) * BK + col1];
#pragma unroll
            for (int ni = 0; ni < 4; ++ni)
                bfr[ni] = *(const bf16x8*)&ldsB[(wn * 64 + ni * 16 + r16) * BK + col1];
#pragma unroll
            for (int mi = 0; mi < 4; ++mi)
#pragma unroll
                for (int ni = 0; ni < 4; ++ni)
                    acc[mi][ni] = __builtin_amdgcn_mfma_f32_16x16x32_bf16(
                        af[mi], bfr[ni], acc[mi][ni], 0, 0, 0);
        }
        __syncthreads();
    }

    const float bv = bias[0];
#pragma unroll
    for (int mi = 0; mi < 4; ++mi) {
        const int row0 = bm + wm * 64 + mi * 16 + quad * 4;
#pragma unroll
        for (int ni = 0; ni < 4; ++ni) {
            const int col = bn + wn * 64 + ni * 16 + r16;
#pragma unroll
            for (int r = 0; r < 4; ++r)
                C[(size_t)(row0 + r) * N2 + col] = acc[mi][ni][r] + bv;
        }
    }
}

// Fallback if workspace is too small for the bf16 copies (correct but slow).
__global__ void naive_kernel(const float* __restrict__ in1, const float* __restrict__ in2,
                             const float* __restrict__ weight, const int* __restrict__ type_index,
                             const float* __restrict__ bias, float* __restrict__ out) {
    int col = blockIdx.x * 16 + threadIdx.x;
    int row = blockIdx.y * 16 + threadIdx.y;
    const float* wr = weight + (size_t)(*type_index) * DK;
    float s = 0.f;
    for (int k = 0; k < DK; ++k)
        s += in1[(size_t)row * DK + k] * wr[k] * in2[(size_t)col * DK + k];
    out[(size_t)row * N2 + col] = s + bias[0];
}

extern "C" void kernel_launch(void* const* d_in, const int* in_sizes, int n_in,
                              void* d_out, int out_size, void* d_ws, size_t ws_size,
                              hipStream_t stream) {
    const float* in1  = (const float*)d_in[0];
    const float* in2  = (const float*)d_in[1];
    const float* wgt  = (const float*)d_in[2];
    const float* bias = (const float*)d_in[3];
    const int*   tix  = (const int*)d_in[4];
    float* out = (float*)d_out;

    const size_t need = 2ull * (N1 + N2) * DK;  // bf16 copies of A(scaled)+B = 16 MB
    if (ws_size >= need) {
        unsigned short* a_bf = (unsigned short*)d_ws;
        unsigned short* b_bf = a_bf + (size_t)N1 * DK;

        const int total4 = (N1 + N2) * DK / 4;
        convert_kernel<<<total4 / 256, 256, 0, stream>>>(in1, in2, wgt, tix, a_bf, b_bf);

        hipError_t e = hipFuncSetAttribute(
            reinterpret_cast<const void*>(gemm_256),
            hipFuncAttributeMaxDynamicSharedMemorySize, 131072);
        if (e == hipSuccess) {
            gemm_256<<<dim3(N2 / 256, N1 / 256), 512, 131072, stream>>>(
                a_bf, b_bf, bias, out);
        } else {
            gemm_bt<<<dim3(N2 / 128, N1 / 128), 256, 0, stream>>>(a_bf, b_bf, bias, out);
        }
    } else {
        dim3 grid(N2 / 16, N1 / 16);
        dim3 blk(16, 16);
        naive_kernel<<<grid, blk, 0, stream>>>(in1, in2, wgt, tix, bias, out);
    }
}